// Round 1
// baseline (548.339 us; speedup 1.0000x reference)
//
#include <hip/hip_runtime.h>
#include <math.h>

// Problem constants
#define NHEAD 16
#define MDIM  1024
#define KD    64
#define BATCH 4
#define SEQ   2048
#define MROWS (BATCH*SEQ)   // 8192 rows for all big GEMMs

using short8 = __attribute__((ext_vector_type(8))) short;  // 8 bf16 (4 VGPRs) - MFMA A/B frag
using f4     = __attribute__((ext_vector_type(4))) float;  // MFMA C/D frag

__device__ inline short f2bf(float x) {
  union { float f; unsigned u; } v; v.f = x;
  unsigned r = v.u + 0x7fffu + ((v.u >> 16) & 1u);  // round-to-nearest-even
  return (short)(r >> 16);
}

// ---------------- weight transpose + convert: W[1024][1024] f32 -> Wt[n][k] bf16 ----------------
__global__ void wtrans_kernel(const float* __restrict__ in, short* __restrict__ out) {
  __shared__ float t[32][33];
  int bx = blockIdx.x * 32, by = blockIdx.y * 32;
  int tx = threadIdx.x, ty = threadIdx.y;   // (32, 8)
#pragma unroll
  for (int i = 0; i < 4; i++)
    t[ty + i * 8][tx] = in[(size_t)(by + ty + i * 8) * MDIM + bx + tx];
  __syncthreads();
#pragma unroll
  for (int i = 0; i < 4; i++)
    out[(size_t)(bx + ty + i * 8) * MDIM + by + tx] = f2bf(t[tx][ty + i * 8]);
}

// ---------------- GEMM: C[8192,1024] = A[8192,1024] * B, B given transposed bf16 [n][k] ----------
// MODE 0: A fp32, epilogue -> Qh/Kh bf16 [B,H,L,64]
// MODE 1: A fp32, epilogue -> Vt bf16 [B,H,64,L]
// MODE 2: A bf16 [8192,1024], epilogue -> fp32 dst = acc + bias[n] + res[row,n]
template <int MODE>
__launch_bounds__(256)
__global__ void gemm_kernel(const void* __restrict__ Ain, const short* __restrict__ Bt,
                            void* __restrict__ dst, const float* __restrict__ bias,
                            const float* __restrict__ res) {
  __shared__ __attribute__((aligned(16))) short As[128 * 40];  // stride 40 pad: 16B-aligned rows, 2-way banks
  __shared__ __attribute__((aligned(16))) short Bs[128 * 40];
  int tid = threadIdx.x;
  int wave = tid >> 6, lane = tid & 63;
  int quad = lane >> 4, low = lane & 15;
  int m0 = blockIdx.x * 128, n0 = blockIdx.y * 128;
  int wr = (wave >> 1) * 64, wc = (wave & 1) * 64;

  f4 acc[4][4];
#pragma unroll
  for (int m = 0; m < 4; m++)
#pragma unroll
    for (int n = 0; n < 4; n++) { acc[m][n][0] = 0.f; acc[m][n][1] = 0.f; acc[m][n][2] = 0.f; acc[m][n][3] = 0.f; }

  for (int k0 = 0; k0 < 1024; k0 += 32) {
    if (MODE == 2) {  // bf16 A source
      const short* Ab = (const short*)Ain;
      int r = tid >> 2, seg = tid & 3;
#pragma unroll
      for (int p = 0; p < 2; p++) {
        int row = p * 64 + r;
        *(int4*)&As[row * 40 + seg * 8] = *(const int4*)&Ab[(size_t)(m0 + row) * 1024 + k0 + seg * 8];
      }
    } else {          // fp32 A source, convert during staging
      const float* Af = (const float*)Ain;
      int r = tid >> 3, seg = tid & 7;
#pragma unroll
      for (int p = 0; p < 4; p++) {
        int row = p * 32 + r;
        float4 v = *(const float4*)&Af[(size_t)(m0 + row) * 1024 + k0 + seg * 4];
        short4 s; s.x = f2bf(v.x); s.y = f2bf(v.y); s.z = f2bf(v.z); s.w = f2bf(v.w);
        *(short4*)&As[row * 40 + seg * 4] = s;
      }
    }
    {
      int r = tid >> 2, seg = tid & 3;
#pragma unroll
      for (int p = 0; p < 2; p++) {
        int row = p * 64 + r;
        *(int4*)&Bs[row * 40 + seg * 8] = *(const int4*)&Bt[(size_t)(n0 + row) * 1024 + k0 + seg * 8];
      }
    }
    __syncthreads();

    short8 af[4], bfr[4];
#pragma unroll
    for (int m = 0; m < 4; m++) af[m] = *(const short8*)&As[(wr + m * 16 + low) * 40 + quad * 8];
#pragma unroll
    for (int n = 0; n < 4; n++) bfr[n] = *(const short8*)&Bs[(wc + n * 16 + low) * 40 + quad * 8];
#pragma unroll
    for (int m = 0; m < 4; m++)
#pragma unroll
      for (int n = 0; n < 4; n++)
        acc[m][n] = __builtin_amdgcn_mfma_f32_16x16x32_bf16(af[m], bfr[n], acc[m][n], 0, 0, 0);
    __syncthreads();
  }

  // epilogue: C row = wr+m*16+quad*4+r2, col = wc+n*16+low
#pragma unroll
  for (int m = 0; m < 4; m++)
#pragma unroll
    for (int n = 0; n < 4; n++)
#pragma unroll
      for (int r2 = 0; r2 < 4; r2++) {
        int gr = m0 + wr + m * 16 + quad * 4 + r2;
        int gc = n0 + wc + n * 16 + low;
        float val = acc[m][n][r2];
        if (MODE == 0) {
          int b = gr >> 11, l = gr & 2047, h = gc >> 6, d = gc & 63;
          ((short*)dst)[(((size_t)(b * NHEAD + h)) * SEQ + l) * KD + d] = f2bf(val);
        } else if (MODE == 1) {
          int b = gr >> 11, l = gr & 2047, h = gc >> 6, d = gc & 63;
          ((short*)dst)[(((size_t)(b * NHEAD + h)) * KD + d) * SEQ + l] = f2bf(val);
        } else {
          ((float*)dst)[(size_t)gr * 1024 + gc] = val + bias[gc] + res[(size_t)gr * 1024 + gc];
        }
      }
}

// ---------------- flash attention: Qh,Kh [B,H,L,64], Vt [B,H,64,L] -> Out bf16 [B,L,H*64] ---------
__launch_bounds__(256)
__global__ void attn_kernel(const short* __restrict__ Qh, const short* __restrict__ Kh,
                            const short* __restrict__ Vt, short* __restrict__ Out) {
  __shared__ __attribute__((aligned(16))) short Ks[64 * 72];
  __shared__ __attribute__((aligned(16))) short Vs[64 * 72];
  __shared__ __attribute__((aligned(16))) short Ps[4][16 * 72];
  int tid = threadIdx.x;
  int wave = tid >> 6, lane = tid & 63, quad = lane >> 4, low = lane & 15;
  int bh = blockIdx.y;
  int q0 = blockIdx.x * 64 + wave * 16;

  const short* Qb = Qh + (size_t)bh * SEQ * KD;
  const short* Kb = Kh + (size_t)bh * SEQ * KD;
  const short* Vb = Vt + (size_t)bh * KD * SEQ;

  // Q fragments (A-layout): lane holds Q[q0+low][d = c*32 + quad*8 + j]
  short8 qf0 = *(const short8*)&Qb[(size_t)(q0 + low) * KD + quad * 8];
  short8 qf1 = *(const short8*)&Qb[(size_t)(q0 + low) * KD + 32 + quad * 8];

  float m_i[4], l_i[4];
  f4 Oacc[4];
#pragma unroll
  for (int r = 0; r < 4; r++) { m_i[r] = -3.0e38f; l_i[r] = 0.f; }
#pragma unroll
  for (int nt = 0; nt < 4; nt++) { Oacc[nt][0] = 0.f; Oacc[nt][1] = 0.f; Oacc[nt][2] = 0.f; Oacc[nt][3] = 0.f; }

  int sr = tid >> 3, sseg = tid & 7;
  const f4 fzero = {0.f, 0.f, 0.f, 0.f};

  for (int k0 = 0; k0 < SEQ; k0 += 64) {
#pragma unroll
    for (int p = 0; p < 2; p++) {
      int row = p * 32 + sr;
      *(int4*)&Ks[row * 72 + sseg * 8] = *(const int4*)&Kb[(size_t)(k0 + row) * KD + sseg * 8];
      *(int4*)&Vs[row * 72 + sseg * 8] = *(const int4*)&Vb[(size_t)row * SEQ + k0 + sseg * 8];
    }
    __syncthreads();

    // S[16 q x 64 keys] in 4 C-tiles; scale by 1/sqrt(64)
    f4 S[4];
#pragma unroll
    for (int nt = 0; nt < 4; nt++) {
      short8 kf0 = *(const short8*)&Ks[(nt * 16 + low) * 72 + quad * 8];
      short8 kf1 = *(const short8*)&Ks[(nt * 16 + low) * 72 + 32 + quad * 8];
      f4 a = __builtin_amdgcn_mfma_f32_16x16x32_bf16(qf0, kf0, fzero, 0, 0, 0);
      a = __builtin_amdgcn_mfma_f32_16x16x32_bf16(qf1, kf1, a, 0, 0, 0);
      S[nt] = a * 0.125f;
    }

    // online softmax (rows = quad*4+r, cols spread over nt and low lanes)
#pragma unroll
    for (int r = 0; r < 4; r++) {
      float v = fmaxf(fmaxf(S[0][r], S[1][r]), fmaxf(S[2][r], S[3][r]));
      v = fmaxf(v, __shfl_xor(v, 1)); v = fmaxf(v, __shfl_xor(v, 2));
      v = fmaxf(v, __shfl_xor(v, 4)); v = fmaxf(v, __shfl_xor(v, 8));
      float mnew = fmaxf(m_i[r], v);
      float alpha = __expf(m_i[r] - mnew);
      float rsum = 0.f;
#pragma unroll
      for (int nt = 0; nt < 4; nt++) {
        float p = __expf(S[nt][r] - mnew);
        rsum += p;
        Ps[wave][(quad * 4 + r) * 72 + nt * 16 + low] = f2bf(p);
      }
      rsum += __shfl_xor(rsum, 1); rsum += __shfl_xor(rsum, 2);
      rsum += __shfl_xor(rsum, 4); rsum += __shfl_xor(rsum, 8);
      l_i[r] = l_i[r] * alpha + rsum;
      m_i[r] = mnew;
#pragma unroll
      for (int nt = 0; nt < 4; nt++) Oacc[nt][r] *= alpha;
    }

    // PV: A = P (round-tripped through LDS), B = V tile
    short8 pf0 = *(const short8*)&Ps[wave][low * 72 + quad * 8];
    short8 pf1 = *(const short8*)&Ps[wave][low * 72 + 32 + quad * 8];
#pragma unroll
    for (int nt = 0; nt < 4; nt++) {
      short8 vf0 = *(const short8*)&Vs[(nt * 16 + low) * 72 + quad * 8];
      short8 vf1 = *(const short8*)&Vs[(nt * 16 + low) * 72 + 32 + quad * 8];
      Oacc[nt] = __builtin_amdgcn_mfma_f32_16x16x32_bf16(pf0, vf0, Oacc[nt], 0, 0, 0);
      Oacc[nt] = __builtin_amdgcn_mfma_f32_16x16x32_bf16(pf1, vf1, Oacc[nt], 0, 0, 0);
    }
    __syncthreads();
  }

  int b = bh >> 4, h = bh & 15;
#pragma unroll
  for (int nt = 0; nt < 4; nt++)
#pragma unroll
    for (int r = 0; r < 4; r++) {
      size_t idx = ((size_t)(b * SEQ + q0 + quad * 4 + r)) * 1024 + h * 64 + nt * 16 + low;
      Out[idx] = f2bf(Oacc[nt][r] / l_i[r]);
    }
}

// ---------------- LayerNorm over rows of x[8192][1024] fp32 -> out fp32 ----------------
__launch_bounds__(256)
__global__ void ln_kernel(const float* __restrict__ x, const float* __restrict__ g,
                          const float* __restrict__ b, float* __restrict__ out) {
  int row = blockIdx.x, tid = threadIdx.x;
  const float4* xr = (const float4*)(x + (size_t)row * 1024);
  float4 v = xr[tid];
  float s = v.x + v.y + v.z + v.w;
  float q = v.x * v.x + v.y * v.y + v.z * v.z + v.w * v.w;
#pragma unroll
  for (int o = 32; o > 0; o >>= 1) { s += __shfl_xor(s, o); q += __shfl_xor(q, o); }
  __shared__ float ss[4], sq[4];
  if ((tid & 63) == 0) { ss[tid >> 6] = s; sq[tid >> 6] = q; }
  __syncthreads();
  if (tid == 0) {
    float S = ss[0] + ss[1] + ss[2] + ss[3];
    float Q = sq[0] + sq[1] + sq[2] + sq[3];
    float mean = S * (1.f / 1024.f);
    float var = Q * (1.f / 1024.f) - mean * mean;
    ss[0] = mean; sq[0] = rsqrtf(var + 1e-5f);
  }
  __syncthreads();
  float mean = ss[0], rs = sq[0];
  const float4* g4 = (const float4*)g;
  const float4* b4 = (const float4*)b;
  float4 gg = g4[tid], bb = b4[tid], o;
  o.x = (v.x - mean) * rs * gg.x + bb.x;
  o.y = (v.y - mean) * rs * gg.y + bb.y;
  o.z = (v.z - mean) * rs * gg.z + bb.z;
  o.w = (v.w - mean) * rs * gg.w + bb.w;
  ((float4*)(out + (size_t)row * 1024))[tid] = o;
}

extern "C" void kernel_launch(void* const* d_in, const int* in_sizes, int n_in,
                              void* d_out, int out_size, void* d_ws, size_t ws_size,
                              hipStream_t stream) {
  const float* q   = (const float*)d_in[0];
  const float* k   = (const float*)d_in[1];
  const float* v   = (const float*)d_in[2];
  const float* Wq  = (const float*)d_in[3];
  const float* Wk  = (const float*)d_in[4];
  const float* Wv  = (const float*)d_in[5];
  const float* fcw = (const float*)d_in[6];
  const float* fcb = (const float*)d_in[7];
  const float* lng = (const float*)d_in[8];
  const float* lnb = (const float*)d_in[9];
  float* out = (float*)d_out;

  // workspace layout (72 MiB total):
  //  0.. 8 MiB : 4 transposed bf16 weights (2 MiB each)
  //  8..24    : Qh bf16 [B,H,L,64]
  // 24..40    : Kh bf16
  // 40..56    : Vt bf16 [B,H,64,L]
  // 56..72    : attn out bf16 [8192,1024]
  //  8..40    : X fp32 [8192,1024] (overlays Qh/Kh, which are dead after attention)
  char* ws = (char*)d_ws;
  const size_t MB = 1024 * 1024;
  short* Wqt = (short*)(ws + 0 * MB);
  short* Wkt = (short*)(ws + 2 * MB);
  short* Wvt = (short*)(ws + 4 * MB);
  short* fct = (short*)(ws + 6 * MB);
  short* Qh  = (short*)(ws + 8 * MB);
  short* Kh  = (short*)(ws + 24 * MB);
  short* Vt  = (short*)(ws + 40 * MB);
  short* Ao  = (short*)(ws + 56 * MB);
  float* X   = (float*)(ws + 8 * MB);

  dim3 tb(32, 8);
  wtrans_kernel<<<dim3(32, 32), tb, 0, stream>>>(Wq, Wqt);
  wtrans_kernel<<<dim3(32, 32), tb, 0, stream>>>(Wk, Wkt);
  wtrans_kernel<<<dim3(32, 32), tb, 0, stream>>>(Wv, Wvt);
  wtrans_kernel<<<dim3(32, 32), tb, 0, stream>>>(fcw, fct);

  gemm_kernel<0><<<dim3(64, 8), 256, 0, stream>>>(q, Wqt, Qh, nullptr, nullptr);
  gemm_kernel<0><<<dim3(64, 8), 256, 0, stream>>>(k, Wkt, Kh, nullptr, nullptr);
  gemm_kernel<1><<<dim3(64, 8), 256, 0, stream>>>(v, Wvt, Vt, nullptr, nullptr);

  attn_kernel<<<dim3(SEQ / 64, BATCH * NHEAD), 256, 0, stream>>>(Qh, Kh, Vt, Ao);

  gemm_kernel<2><<<dim3(64, 8), 256, 0, stream>>>(Ao, fct, X, fcb, q);

  ln_kernel<<<MROWS, 256, 0, stream>>>(X, lng, lnb, out);
}